// Round 9
// baseline (11.891 us; speedup 1.0000x reference)
//
#include <hip/hip_runtime.h>

#define BTOT 32768
#define INV2PI 0.15915494309189535f

// ======== compile-time Pauli algebra (Heisenberg back-propagation) ========
// Pauli codes: 0=I, 1=X, 2=Y, 3=Z. Strings packed 2 bits/qubit (qubit j at bits 2j).
namespace ct {
constexpr int PMUL[4][4] = {{0,1,2,3},{1,0,3,2},{2,3,0,1},{3,2,1,0}};
constexpr int PPH [4][4] = {{0,0,0,0},{0,0,1,3},{0,3,0,1},{0,1,3,0}};  // phase as power of i

// Conjugation images through one CNOT block (odd rank then even rank, backward):
constexpr unsigned A_STR[8] = {0x3u, 0xFu, 0x3Fu, 0xF0u, 0x3F0u, 0xF00u, 0x3F00u, 0xF000u};
// Z0 | Z0Z1 | Z0Z1Z2 | Z2Z3 | Z2Z3Z4 | Z4Z5 | Z4Z5Z6 | Z6Z7
constexpr unsigned B_STR[8] = {0x5u, 0x54u, 0x50u, 0x540u, 0x500u, 0x5400u, 0x5000u, 0x4000u};
// X0X1 | X1X2X3 | X2X3 | X3X4X5 | X4X5 | X5X6X7 | X6X7 | X7

struct Terms {
    int n; int w; int supp[3];
    float sgn[8]; unsigned char sbits[8]; unsigned char xm[8]; unsigned char zm[8];
};

constexpr Terms gen(int q, bool xpart) {
    Terms T{};
    const unsigned base = xpart ? B_STR[q] : A_STR[q];
    T.w = 0;
    for (int j = 0; j < 8; ++j)
        if ((base >> (2*j)) & 3u) { T.supp[T.w] = j; T.w++; }
    T.n = 0;
    for (int b = 0; b < (1 << T.w); ++b) {
        unsigned str = 0; int ph = 0; float sg = 1.0f;
        for (int i = 0; i < T.w; ++i) {
            const int j = T.supp[i];
            const int pj = (base >> (2*j)) & 3;
            const bool sbr = ((b >> i) & 1) != 0;
            unsigned f = 0;
            if (pj == 3) { f = sbr ? B_STR[j] : A_STR[j]; if (sbr) sg = -sg; }
            else         { f = sbr ? A_STR[j] : B_STR[j]; }
            unsigned r = 0;
            for (int k = 0; k < 8; ++k) {
                const int pa = (str >> (2*k)) & 3, pb = (f >> (2*k)) & 3;
                r |= (unsigned)PMUL[pa][pb] << (2*k);
                ph = (ph + PPH[pa][pb]) & 3;
            }
            str = r;
        }
        bool dead = false; unsigned xm = 0, zm = 0;
        for (int k = 0; k < 8; ++k) {
            const int p = (str >> (2*k)) & 3;
            if (p == 2) dead = true;
            else if (p == 1) xm |= 1u << k;
            else if (p == 3) zm |= 1u << k;
        }
        if (ph & 1) dead = true;
        if (dead) continue;
        if (ph == 2) sg = -sg;
        T.sgn[T.n] = sg; T.sbits[T.n] = (unsigned char)b;
        T.xm[T.n] = (unsigned char)xm; T.zm[T.n] = (unsigned char)zm;
        T.n++;
    }
    return T;
}

constexpr Terms TA[8] = {gen(0,false),gen(1,false),gen(2,false),gen(3,false),
                         gen(4,false),gen(5,false),gen(6,false),gen(7,false)};
constexpr Terms TB[8] = {gen(0,true),gen(1,true),gen(2,true),gen(3,true),
                         gen(4,true),gen(5,true),gen(6,true),gen(7,true)};

constexpr unsigned suppmask(unsigned str) {
    unsigned m = 0;
    for (int j = 0; j < 8; ++j) if ((str >> (2*j)) & 3u) m |= 1u << j;
    return m;
}
template<int Q>
constexpr unsigned qmask() { return suppmask(A_STR[Q]) | suppmask(B_STR[Q]); }
} // namespace ct

__device__ __forceinline__ float ftanh(float x) {
    float e = __builtin_amdgcn_exp2f(x * 2.8853900817779268f);  // e^(2x)
    return (e - 1.0f) * __builtin_amdgcn_rcpf(e + 1.0f);
}
__device__ __forceinline__ float fcos(float x) { return __builtin_amdgcn_cosf(x * INV2PI); }
__device__ __forceinline__ float fsin(float x) { return __builtin_amdgcn_sinf(x * INV2PI); }

// evaluate <Z_q> before final tanh (tables folded at compile time)
template<int Q>
__device__ __forceinline__ float eval_q(const float c1[8], const float s1[8],
                                        const float xv[8], const float zv[8],
                                        float c2, float s2)
{
    float EA = 0.0f;
    #pragma unroll
    for (int t = 0; t < 8; ++t) {
        if (t < ct::TA[Q].n) {
            float cf = ct::TA[Q].sgn[t];
            #pragma unroll
            for (int i = 0; i < 3; ++i)
                if (i < ct::TA[Q].w)
                    cf *= ((ct::TA[Q].sbits[t] >> i) & 1) ? s1[ct::TA[Q].supp[i]]
                                                          : c1[ct::TA[Q].supp[i]];
            #pragma unroll
            for (int j = 0; j < 8; ++j) {
                if ((ct::TA[Q].xm[t] >> j) & 1) cf *= xv[j];
                if ((ct::TA[Q].zm[t] >> j) & 1) cf *= zv[j];
            }
            EA += cf;
        }
    }
    float EB = 0.0f;
    #pragma unroll
    for (int t = 0; t < 8; ++t) {
        if (t < ct::TB[Q].n) {
            float cf = ct::TB[Q].sgn[t];
            #pragma unroll
            for (int i = 0; i < 3; ++i)
                if (i < ct::TB[Q].w)
                    cf *= ((ct::TB[Q].sbits[t] >> i) & 1) ? s1[ct::TB[Q].supp[i]]
                                                          : c1[ct::TB[Q].supp[i]];
            #pragma unroll
            for (int j = 0; j < 8; ++j) {
                if ((ct::TB[Q].xm[t] >> j) & 1) cf *= xv[j];
                if ((ct::TB[Q].zm[t] >> j) & 1) cf *= zv[j];
            }
            EB += cf;
        }
    }
    return fmaf(c2, EA, -(s2 * EB));
}

// phase 1: embed qubit Q for this lane's sample -> xz[Q][lane]
template<int Q>
__device__ __forceinline__ void embed_q(
    const float4 xa, const float4 xb, const float* __restrict__ W1,
    const float* __restrict__ b1, int lane, float2 (*xz)[64])
{
    float a = b1[Q];
    a = fmaf(xa.x, W1[Q*8+0], a); a = fmaf(xa.y, W1[Q*8+1], a);
    a = fmaf(xa.z, W1[Q*8+2], a); a = fmaf(xa.w, W1[Q*8+3], a);
    a = fmaf(xb.x, W1[Q*8+4], a); a = fmaf(xb.y, W1[Q*8+5], a);
    a = fmaf(xb.z, W1[Q*8+6], a); a = fmaf(xb.w, W1[Q*8+7], a);
    const float th = ftanh(a);
    float2 e; e.x = fcos(th); e.y = -fsin(th);
    xz[Q][lane] = e;
}

// phase 2: trig for support union + term eval + tanh -> ybuf[Q][lane]
template<int Q>
__device__ __forceinline__ void eval_phase(
    const float* __restrict__ qw, int lane,
    const float xv[8], const float zv[8], float (*ybuf)[64])
{
    constexpr unsigned m = ct::qmask<Q>();
    float c1[8], s1[8];
    #pragma unroll
    for (int j = 0; j < 8; ++j) {
        if ((m >> j) & 1) { c1[j] = fcos(qw[j]); s1[j] = fsin(qw[j]); }
    }
    const float c2 = fcos(qw[8+Q]), s2 = fsin(qw[8+Q]);
    ybuf[Q][lane] = ftanh(eval_q<Q>(c1, s1, xv, zv, c2, s2));
}

__global__ __launch_bounds__(512) void vqc_net(
    const float* __restrict__ x,
    const float* __restrict__ W_pi1, const float* __restrict__ b_pi1,
    const float* __restrict__ qw_pi,
    const float* __restrict__ W_pi2, const float* __restrict__ b_pi2,
    const float* __restrict__ W_v1, const float* __restrict__ b_v1,
    const float* __restrict__ qw_v,
    const float* __restrict__ W_v2, const float* __restrict__ b_v2,
    float* __restrict__ out)
{
    __shared__ float2 xz[8][64];     // embed factors  (4 KB)
    __shared__ float  ybuf[8][64];   // tanh'd <Z_q>   (2 KB)
    __shared__ float4 obuf[64];      // pi-output transpose (1 KB)

    const int tid = threadIdx.x;
    const int lane = tid & 63;
    const int w = tid >> 6;                    // 0..7: this wave's qubit
    const int item = blockIdx.x * 64 + lane;   // block-uniform branch (32768 % 64 == 0)
    const int branch = item >> 15;             // 0 = pi, 1 = v
    const int s = item & (BTOT - 1);

    const float* W1 = branch ? W_v1 : W_pi1;
    const float* b1 = branch ? b_v1 : b_pi1;
    const float* qw = branch ? qw_v : qw_pi;

    // per-lane sample row (only per-lane global load)
    const float4* xr = (const float4*)(x + s * 8);
    const float4 xa = xr[0], xb = xr[1];

    switch (w) {
        case 0: embed_q<0>(xa, xb, W1, b1, lane, xz); break;
        case 1: embed_q<1>(xa, xb, W1, b1, lane, xz); break;
        case 2: embed_q<2>(xa, xb, W1, b1, lane, xz); break;
        case 3: embed_q<3>(xa, xb, W1, b1, lane, xz); break;
        case 4: embed_q<4>(xa, xb, W1, b1, lane, xz); break;
        case 5: embed_q<5>(xa, xb, W1, b1, lane, xz); break;
        case 6: embed_q<6>(xa, xb, W1, b1, lane, xz); break;
        default: embed_q<7>(xa, xb, W1, b1, lane, xz); break;
    }
    __syncthreads();

    float xv[8], zv[8];
    #pragma unroll
    for (int j = 0; j < 8; ++j) {
        const float2 t = xz[j][lane];
        xv[j] = t.x; zv[j] = t.y;
    }

    switch (w) {
        case 0: eval_phase<0>(qw, lane, xv, zv, ybuf); break;
        case 1: eval_phase<1>(qw, lane, xv, zv, ybuf); break;
        case 2: eval_phase<2>(qw, lane, xv, zv, ybuf); break;
        case 3: eval_phase<3>(qw, lane, xv, zv, ybuf); break;
        case 4: eval_phase<4>(qw, lane, xv, zv, ybuf); break;
        case 5: eval_phase<5>(qw, lane, xv, zv, ybuf); break;
        case 6: eval_phase<6>(qw, lane, xv, zv, ybuf); break;
        default: eval_phase<7>(qw, lane, xv, zv, ybuf); break;
    }
    __syncthreads();

    if (branch == 0) {
        if (w < 4) {
            float o = b_pi2[w];
            #pragma unroll
            for (int j = 0; j < 8; ++j) o = fmaf(ybuf[j][lane], W_pi2[w*8+j], o);
            ((float*)&obuf[lane])[w] = o;
        }
        __syncthreads();
        if (w == 0) *(float4*)(out + s * 4) = obuf[lane];
    } else {
        if (w == 0) {
            float o = b_v2[0];
            #pragma unroll
            for (int j = 0; j < 8; ++j) o = fmaf(ybuf[j][lane], W_v2[j], o);
            out[4 * BTOT + s] = o;
        }
    }
}

extern "C" void kernel_launch(void* const* d_in, const int* in_sizes, int n_in,
                              void* d_out, int out_size, void* d_ws, size_t ws_size,
                              hipStream_t stream) {
    const float* x     = (const float*)d_in[0];
    const float* W_pi1 = (const float*)d_in[1];
    const float* b_pi1 = (const float*)d_in[2];
    const float* qw_pi = (const float*)d_in[3];
    const float* W_pi2 = (const float*)d_in[4];
    const float* b_pi2 = (const float*)d_in[5];
    const float* W_v1  = (const float*)d_in[6];
    const float* b_v1  = (const float*)d_in[7];
    const float* qw_v  = (const float*)d_in[8];
    const float* W_v2  = (const float*)d_in[9];
    const float* b_v2  = (const float*)d_in[10];
    float* out = (float*)d_out;

    const int blocks = (2 * BTOT) / 64;  // 64 items/block, 8 waves (1 qubit each)
    vqc_net<<<blocks, 512, 0, stream>>>(
        x, W_pi1, b_pi1, qw_pi, W_pi2, b_pi2,
        W_v1, b_v1, qw_v, W_v2, b_v2, out);
}

// Round 10
// 9.440 us; speedup vs baseline: 1.2596x; 1.2596x over previous
//
#include <hip/hip_runtime.h>

#define BTOT 32768
#define INV2PI 0.15915494309189535f

// ======== compile-time Pauli algebra (Heisenberg back-propagation) ========
// Pauli codes: 0=I, 1=X, 2=Y, 3=Z. Strings packed 2 bits/qubit (qubit j at bits 2j).
namespace ct {
constexpr int PMUL[4][4] = {{0,1,2,3},{1,0,3,2},{2,3,0,1},{3,2,1,0}};
constexpr int PPH [4][4] = {{0,0,0,0},{0,0,1,3},{0,3,0,1},{0,1,3,0}};  // phase as power of i

// Conjugation images through one CNOT block (odd rank then even rank, backward):
constexpr unsigned A_STR[8] = {0x3u, 0xFu, 0x3Fu, 0xF0u, 0x3F0u, 0xF00u, 0x3F00u, 0xF000u};
// Z0 | Z0Z1 | Z0Z1Z2 | Z2Z3 | Z2Z3Z4 | Z4Z5 | Z4Z5Z6 | Z6Z7
constexpr unsigned B_STR[8] = {0x5u, 0x54u, 0x50u, 0x540u, 0x500u, 0x5400u, 0x5000u, 0x4000u};
// X0X1 | X1X2X3 | X2X3 | X3X4X5 | X4X5 | X5X6X7 | X6X7 | X7

struct Terms {
    int n; int w; int supp[3];
    float sgn[8]; unsigned char sbits[8]; unsigned char xm[8]; unsigned char zm[8];
};

constexpr Terms gen(int q, bool xpart) {
    Terms T{};
    const unsigned base = xpart ? B_STR[q] : A_STR[q];
    T.w = 0;
    for (int j = 0; j < 8; ++j)
        if ((base >> (2*j)) & 3u) { T.supp[T.w] = j; T.w++; }
    T.n = 0;
    for (int b = 0; b < (1 << T.w); ++b) {
        unsigned str = 0; int ph = 0; float sg = 1.0f;
        for (int i = 0; i < T.w; ++i) {
            const int j = T.supp[i];
            const int pj = (base >> (2*j)) & 3;
            const bool sbr = ((b >> i) & 1) != 0;
            unsigned f = 0;
            if (pj == 3) { f = sbr ? B_STR[j] : A_STR[j]; if (sbr) sg = -sg; }
            else         { f = sbr ? A_STR[j] : B_STR[j]; }
            unsigned r = 0;
            for (int k = 0; k < 8; ++k) {
                const int pa = (str >> (2*k)) & 3, pb = (f >> (2*k)) & 3;
                r |= (unsigned)PMUL[pa][pb] << (2*k);
                ph = (ph + PPH[pa][pb]) & 3;
            }
            str = r;
        }
        bool dead = false; unsigned xm = 0, zm = 0;
        for (int k = 0; k < 8; ++k) {
            const int p = (str >> (2*k)) & 3;
            if (p == 2) dead = true;
            else if (p == 1) xm |= 1u << k;
            else if (p == 3) zm |= 1u << k;
        }
        if (ph & 1) dead = true;
        if (dead) continue;
        if (ph == 2) sg = -sg;
        T.sgn[T.n] = sg; T.sbits[T.n] = (unsigned char)b;
        T.xm[T.n] = (unsigned char)xm; T.zm[T.n] = (unsigned char)zm;
        T.n++;
    }
    return T;
}

constexpr Terms TA[8] = {gen(0,false),gen(1,false),gen(2,false),gen(3,false),
                         gen(4,false),gen(5,false),gen(6,false),gen(7,false)};
constexpr Terms TB[8] = {gen(0,true),gen(1,true),gen(2,true),gen(3,true),
                         gen(4,true),gen(5,true),gen(6,true),gen(7,true)};

constexpr unsigned suppmask(unsigned str) {
    unsigned m = 0;
    for (int j = 0; j < 8; ++j) if ((str >> (2*j)) & 3u) m |= 1u << j;
    return m;
}
constexpr unsigned qmask(int q) { return suppmask(A_STR[q]) | suppmask(B_STR[q]); }
} // namespace ct

__device__ __forceinline__ float ftanh(float x) {
    float e = __builtin_amdgcn_exp2f(x * 2.8853900817779268f);  // e^(2x)
    return (e - 1.0f) * __builtin_amdgcn_rcpf(e + 1.0f);
}
__device__ __forceinline__ float fcos(float x) { return __builtin_amdgcn_cosf(x * INV2PI); }
__device__ __forceinline__ float fsin(float x) { return __builtin_amdgcn_sinf(x * INV2PI); }

// evaluate <Z_q> before final tanh (tables folded at compile time)
template<int Q>
__device__ __forceinline__ float eval_q(const float c1[8], const float s1[8],
                                        const float xv[8], const float zv[8],
                                        float c2, float s2)
{
    float EA = 0.0f;
    #pragma unroll
    for (int t = 0; t < 8; ++t) {
        if (t < ct::TA[Q].n) {
            float cf = ct::TA[Q].sgn[t];
            #pragma unroll
            for (int i = 0; i < 3; ++i)
                if (i < ct::TA[Q].w)
                    cf *= ((ct::TA[Q].sbits[t] >> i) & 1) ? s1[ct::TA[Q].supp[i]]
                                                          : c1[ct::TA[Q].supp[i]];
            #pragma unroll
            for (int j = 0; j < 8; ++j) {
                if ((ct::TA[Q].xm[t] >> j) & 1) cf *= xv[j];
                if ((ct::TA[Q].zm[t] >> j) & 1) cf *= zv[j];
            }
            EA += cf;
        }
    }
    float EB = 0.0f;
    #pragma unroll
    for (int t = 0; t < 8; ++t) {
        if (t < ct::TB[Q].n) {
            float cf = ct::TB[Q].sgn[t];
            #pragma unroll
            for (int i = 0; i < 3; ++i)
                if (i < ct::TB[Q].w)
                    cf *= ((ct::TB[Q].sbits[t] >> i) & 1) ? s1[ct::TB[Q].supp[i]]
                                                          : c1[ct::TB[Q].supp[i]];
            #pragma unroll
            for (int j = 0; j < 8; ++j) {
                if ((ct::TB[Q].xm[t] >> j) & 1) cf *= xv[j];
                if ((ct::TB[Q].zm[t] >> j) & 1) cf *= zv[j];
            }
            EB += cf;
        }
    }
    return fmaf(c2, EA, -(s2 * EB));
}

// phase 1 (wave W, qubits 2W/2W+1): gate trig (in x-load shadow) + embed -> xz
template<int W>
__device__ __forceinline__ void embed_pair(
    const float4 xa, const float4 xb,
    const float* __restrict__ W1, const float* __restrict__ b1,
    const float* __restrict__ qw,
    int lane, float2 (*xz)[64],
    float c1[8], float s1[8], float2& cs2a, float2& cs2b)
{
    constexpr int j0 = 2*W, j1 = 2*W + 1;
    constexpr unsigned m = ct::qmask(j0) | ct::qmask(j1);
    // wave-uniform trig first: overlaps the in-flight x load
    #pragma unroll
    for (int j = 0; j < 8; ++j)
        if ((m >> j) & 1) { c1[j] = fcos(qw[j]); s1[j] = fsin(qw[j]); }
    cs2a.x = fcos(qw[8+j0]); cs2a.y = fsin(qw[8+j0]);
    cs2b.x = fcos(qw[8+j1]); cs2b.y = fsin(qw[8+j1]);

    float a0 = b1[j0], a1 = b1[j1];
    a0 = fmaf(xa.x, W1[j0*8+0], a0); a0 = fmaf(xa.y, W1[j0*8+1], a0);
    a0 = fmaf(xa.z, W1[j0*8+2], a0); a0 = fmaf(xa.w, W1[j0*8+3], a0);
    a0 = fmaf(xb.x, W1[j0*8+4], a0); a0 = fmaf(xb.y, W1[j0*8+5], a0);
    a0 = fmaf(xb.z, W1[j0*8+6], a0); a0 = fmaf(xb.w, W1[j0*8+7], a0);
    a1 = fmaf(xa.x, W1[j1*8+0], a1); a1 = fmaf(xa.y, W1[j1*8+1], a1);
    a1 = fmaf(xa.z, W1[j1*8+2], a1); a1 = fmaf(xa.w, W1[j1*8+3], a1);
    a1 = fmaf(xb.x, W1[j1*8+4], a1); a1 = fmaf(xb.y, W1[j1*8+5], a1);
    a1 = fmaf(xb.z, W1[j1*8+6], a1); a1 = fmaf(xb.w, W1[j1*8+7], a1);
    const float th0 = ftanh(a0), th1 = ftanh(a1);
    float2 e0; e0.x = fcos(th0); e0.y = -fsin(th0);
    float2 e1; e1.x = fcos(th1); e1.y = -fsin(th1);
    xz[j0][lane] = e0;
    xz[j1][lane] = e1;
}

// phase 2: term eval + tanh -> ybuf
template<int W>
__device__ __forceinline__ void eval_pair(
    const float c1[8], const float s1[8], float2 cs2a, float2 cs2b,
    const float xv[8], const float zv[8], int lane, float (*ybuf)[64])
{
    constexpr int j0 = 2*W, j1 = 2*W + 1;
    ybuf[j0][lane] = ftanh(eval_q<j0>(c1, s1, xv, zv, cs2a.x, cs2a.y));
    ybuf[j1][lane] = ftanh(eval_q<j1>(c1, s1, xv, zv, cs2b.x, cs2b.y));
}

__global__ __launch_bounds__(256) void vqc_net(
    const float* __restrict__ x,
    const float* __restrict__ W_pi1, const float* __restrict__ b_pi1,
    const float* __restrict__ qw_pi,
    const float* __restrict__ W_pi2, const float* __restrict__ b_pi2,
    const float* __restrict__ W_v1, const float* __restrict__ b_v1,
    const float* __restrict__ qw_v,
    const float* __restrict__ W_v2, const float* __restrict__ b_v2,
    float* __restrict__ out)
{
    __shared__ float2 xz[8][64];     // embed factors  (4 KB)
    __shared__ float  ybuf[8][64];   // tanh'd <Z_q>   (2 KB)

    const int tid = threadIdx.x;
    const int lane = tid & 63;
    const int w = tid >> 6;                    // 0..3: this wave's qubit pair
    const int item = blockIdx.x * 64 + lane;   // block-uniform branch (32768 % 64 == 0)
    const int branch = item >> 15;             // 0 = pi, 1 = v
    const int s = item & (BTOT - 1);

    const float* W1 = branch ? W_v1 : W_pi1;
    const float* b1 = branch ? b_v1 : b_pi1;
    const float* qw = branch ? qw_v : qw_pi;

    // per-lane sample row: issue loads first, trig fills the shadow
    const float4* xr = (const float4*)(x + s * 8);
    const float4 xa = xr[0], xb = xr[1];

    float c1[8], s1[8];
    float2 cs2a, cs2b;
    switch (w) {
        case 0:  embed_pair<0>(xa, xb, W1, b1, qw, lane, xz, c1, s1, cs2a, cs2b); break;
        case 1:  embed_pair<1>(xa, xb, W1, b1, qw, lane, xz, c1, s1, cs2a, cs2b); break;
        case 2:  embed_pair<2>(xa, xb, W1, b1, qw, lane, xz, c1, s1, cs2a, cs2b); break;
        default: embed_pair<3>(xa, xb, W1, b1, qw, lane, xz, c1, s1, cs2a, cs2b); break;
    }
    __syncthreads();

    float xv[8], zv[8];
    #pragma unroll
    for (int j = 0; j < 8; ++j) {
        const float2 t = xz[j][lane];
        xv[j] = t.x; zv[j] = t.y;
    }

    switch (w) {
        case 0:  eval_pair<0>(c1, s1, cs2a, cs2b, xv, zv, lane, ybuf); break;
        case 1:  eval_pair<1>(c1, s1, cs2a, cs2b, xv, zv, lane, ybuf); break;
        case 2:  eval_pair<2>(c1, s1, cs2a, cs2b, xv, zv, lane, ybuf); break;
        default: eval_pair<3>(c1, s1, cs2a, cs2b, xv, zv, lane, ybuf); break;
    }
    __syncthreads();

    if (branch == 0) {
        // wave w writes logit w directly (16B-stride stores, fire-and-forget)
        float o = b_pi2[w];
        #pragma unroll
        for (int j = 0; j < 8; ++j) o = fmaf(ybuf[j][lane], W_pi2[w*8+j], o);
        out[s * 4 + w] = o;
    } else {
        if (w == 0) {
            float o = b_v2[0];
            #pragma unroll
            for (int j = 0; j < 8; ++j) o = fmaf(ybuf[j][lane], W_v2[j], o);
            out[4 * BTOT + s] = o;
        }
    }
}

extern "C" void kernel_launch(void* const* d_in, const int* in_sizes, int n_in,
                              void* d_out, int out_size, void* d_ws, size_t ws_size,
                              hipStream_t stream) {
    const float* x     = (const float*)d_in[0];
    const float* W_pi1 = (const float*)d_in[1];
    const float* b_pi1 = (const float*)d_in[2];
    const float* qw_pi = (const float*)d_in[3];
    const float* W_pi2 = (const float*)d_in[4];
    const float* b_pi2 = (const float*)d_in[5];
    const float* W_v1  = (const float*)d_in[6];
    const float* b_v1  = (const float*)d_in[7];
    const float* qw_v  = (const float*)d_in[8];
    const float* W_v2  = (const float*)d_in[9];
    const float* b_v2  = (const float*)d_in[10];
    float* out = (float*)d_out;

    const int blocks = (2 * BTOT) / 64;  // 64 items/block, 4 waves (2 qubits each)
    vqc_net<<<blocks, 256, 0, stream>>>(
        x, W_pi1, b_pi1, qw_pi, W_pi2, b_pi2,
        W_v1, b_v1, qw_v, W_v2, b_v2, out);
}